// Round 6
// baseline (643.370 us; speedup 1.0000x reference)
//
#include <hip/hip_runtime.h>

typedef unsigned short u16;
typedef unsigned int u32;

#define Bn 32
#define Cn 64
#define Hn 128
#define Wn 128
#define QD 8
#define HWn (Hn*Wn)
#define NEGV (-1e4f)

__device__ __forceinline__ float bf2f(u16 u){
  u32 i = ((u32)u) << 16; float f; __builtin_memcpy(&f, &i, 4); return f;
}
__device__ __forceinline__ float bfLO(u32 x){
  u32 i = x << 16; float f; __builtin_memcpy(&f, &i, 4); return f;
}
__device__ __forceinline__ float bfHI(u32 x){
  u32 i = x & 0xFFFF0000u; float f; __builtin_memcpy(&f, &i, 4); return f;
}
__device__ __forceinline__ u16 f2bf(float f){
  u32 i; __builtin_memcpy(&i, &f, 4);
  return (u16)((i + 0x7FFFu + ((i >> 16) & 1u)) >> 16);
}
__device__ __forceinline__ u32 pack2bf(float lo, float hi){
  return (u32)f2bf(lo) | ((u32)f2bf(hi) << 16);
}
__device__ __forceinline__ float softplusf(float x){
  return fmaxf(x, 0.0f) + log1pf(expf(-fabsf(x)));
}
__device__ __forceinline__ float rd_any(const void* p, int i, bool bf){
  return bf ? bf2f(((const u16*)p)[i]) : ((const float*)p)[i];
}

// ---------------------------------------------------------------------------
// Fused dtype-detect + weight convert/transpose (saves one launch).
// Detector: bits 8..15 of a dword are a bf16 sign/exp byte if packed bf16
// (concentrated near 0x38..0x40 ex-sign), uniform if f32 mantissa.
__global__ void k_setup(const void* wq, const void* bq, const void* wk, const void* bk,
                        const void* wv, const void* bv, const void* gamma,
                        int* __restrict__ flag,
                        float* __restrict__ Wall, float* __restrict__ biasv,
                        float* __restrict__ gammaF){
  __shared__ int cnt;
  int t = threadIdx.x;
  if (t == 0) cnt = 0;
  __syncthreads();
  {
    u32 d = ((const u32*)wq)[t];          // 256 dwords = 1KB, safe for both dtypes
    u32 m = (d >> 8) & 0x7Fu;
    if (m >= 0x38u && m <= 0x40u) atomicAdd(&cnt, 1);
  }
  __syncthreads();
  bool bf = (cnt >= 128);
  if (t == 0) flag[0] = bf ? 1 : 0;
  for (int idx = t; idx < Cn*80; idx += 256){
    int c = idx / 80, j = idx % 80;
    float v;
    if (j < 8)       v = rd_any(wq, j*Cn + c, bf);
    else if (j < 16) v = rd_any(wk, (j-8)*Cn + c, bf);
    else             v = rd_any(wv, (j-16)*Cn + c, bf);
    Wall[idx] = v;
  }
  for (int j = t; j < 80; j += 256){
    float v = (j < 8) ? rd_any(bq, j, bf) : (j < 16) ? rd_any(bk, j-8, bf) : rd_any(bv, j-16, bf);
    biasv[j] = v;
  }
  if (t == 0) gammaF[0] = rd_any(gamma, 0, bf);
}

// ---------------------------------------------------------------------------
// Projection v2: per-pixel 80-output 1x1 conv. Q,K -> softplus bf16/bf16; V -> bf16.
// bf16 path: LDS x-tile (512 px x 64 c = 64KB), outputs computed in 3 register
// groups (QK:32acc, V0:64acc, V1:64acc) so nothing spills (R5: VGPR=52 vs 80
// live accs => scratch spills were the 145us pathology). 2 px/thread via u32.
__global__ __launch_bounds__(256, 2) void k_proj(const void* __restrict__ xin,
    const int* __restrict__ flag, const float* __restrict__ Wall,
    const float* __restrict__ biasv, u16* __restrict__ Qb,
    u16* __restrict__ Kb, u16* __restrict__ Vb){
  __shared__ u16 xl[Cn*512];                     // [c][px] 64KB
  int t = threadIdx.x;
  int b = blockIdx.x >> 5;                       // 32 blocks per batch
  int p0 = (blockIdx.x & 31) * 512;

  if (flag[0]){
    // ---- stage x tile, uint4 coalesced: 4096 16B-chunks, 16/thread
    const u32* xg = (const u32*)((const u16*)xin + (size_t)b*Cn*HWn + p0);
    u32* xls = (u32*)xl;
    #pragma unroll
    for (int r=0;r<16;r++){
      int f = r*256 + t;                         // 0..4095
      int c = f >> 6, qd = f & 63;
      *(uint4*)&xls[c*256 + qd*4] = *(const uint4*)&xg[(size_t)c*(HWn/2) + qd*4];
    }
    __syncthreads();

    // ---- Group 0: Q and K (32 accumulators)
    {
      float aq[QD][2], ak[QD][2];
      #pragma unroll
      for (int j=0;j<QD;j++){
        aq[j][0]=biasv[j];    aq[j][1]=biasv[j];
        ak[j][0]=biasv[QD+j]; ak[j][1]=biasv[QD+j];
      }
      #pragma unroll 2
      for (int c=0;c<Cn;c++){
        u32 xv = ((u32*)xl)[c*256 + t];
        float x0 = bfLO(xv), x1 = bfHI(xv);
        const float* wc = Wall + c*80;
        #pragma unroll
        for (int j=0;j<QD;j++){
          float wj = wc[j], wk8 = wc[QD+j];
          aq[j][0] = fmaf(x0, wj, aq[j][0]);  aq[j][1] = fmaf(x1, wj, aq[j][1]);
          ak[j][0] = fmaf(x0, wk8, ak[j][0]); ak[j][1] = fmaf(x1, wk8, ak[j][1]);
        }
      }
      #pragma unroll
      for (int j=0;j<QD;j++){
        size_t o = ((size_t)(b*QD + j)*HWn + p0)/2 + t;
        ((u32*)Qb)[o] = pack2bf(softplusf(aq[j][0]), softplusf(aq[j][1]));
        ((u32*)Kb)[o] = pack2bf(softplusf(ak[j][0]), softplusf(ak[j][1]));
      }
    }
    // ---- Groups 1,2: V halves (64 accumulators each)
    for (int g=0; g<2; ++g){
      float av[32][2];
      #pragma unroll
      for (int j=0;j<32;j++){ av[j][0]=biasv[16+g*32+j]; av[j][1]=av[j][0]; }
      #pragma unroll 2
      for (int c=0;c<Cn;c++){
        u32 xv = ((u32*)xl)[c*256 + t];
        float x0 = bfLO(xv), x1 = bfHI(xv);
        const float* wc = Wall + c*80 + 16 + g*32;
        #pragma unroll
        for (int j=0;j<32;j++){
          float wj = wc[j];
          av[j][0] = fmaf(x0, wj, av[j][0]);  av[j][1] = fmaf(x1, wj, av[j][1]);
        }
      }
      #pragma unroll
      for (int j=0;j<32;j++){
        size_t o = ((size_t)(b*Cn + g*32 + j)*HWn + p0)/2 + t;
        ((u32*)Vb)[o] = pack2bf(av[j][0], av[j][1]);
      }
    }
  } else {
    // ---- f32 fallback: old register-walk path, 2 px/thread serially
    for (int sub=0; sub<2; ++sub){
      int p = p0 + sub*256 + t;
      float accQ[QD], accK[QD], accV[Cn];
      #pragma unroll
      for (int j=0;j<QD;j++){ accQ[j]=biasv[j]; accK[j]=biasv[QD+j]; }
      #pragma unroll
      for (int j=0;j<Cn;j++) accV[j]=biasv[16+j];
      size_t xoff = (size_t)b*Cn*HWn + p;
      for (int c=0;c<Cn;c++){
        float xv = ((const float*)xin)[xoff + (size_t)c*HWn];
        const float* wc = Wall + c*80;
        #pragma unroll
        for (int j=0;j<QD;j++) accQ[j] = fmaf(xv, wc[j], accQ[j]);
        #pragma unroll
        for (int j=0;j<QD;j++) accK[j] = fmaf(xv, wc[QD+j], accK[j]);
        #pragma unroll
        for (int j=0;j<Cn;j++) accV[j] = fmaf(xv, wc[16+j], accV[j]);
      }
      size_t qbase = (size_t)b*QD*HWn + p;
      #pragma unroll
      for (int j=0;j<QD;j++){
        Qb[qbase + (size_t)j*HWn] = f2bf(softplusf(accQ[j]));
        Kb[qbase + (size_t)j*HWn] = f2bf(softplusf(accK[j]));
      }
      size_t vbase = (size_t)b*Cn*HWn + p;
      #pragma unroll
      for (int j=0;j<Cn;j++) Vb[vbase + (size_t)j*HWn] = f2bf(accV[j]);
    }
  }
}

// ---------------------------------------------------------------------------
// Fused M-reduction. Block = (b, 4-channel tile), 256 threads, loop 8 h-tiles.
//   Mrow[b,c,q,h] = sum_w V[c,h,w]*K[q,h,w]   (completes per h-tile)
//   Mcol[b,c,q,w] = sum_h V[c,h,w]*K[q,h,w]   (register-accumulated, no atomics)
// LDS tiles bf16 with XOR-(h<<2) swizzle at 4-u16 granularity.
__global__ __launch_bounds__(256, 2) void k_msum(const u16* __restrict__ Vb,
    const u16* __restrict__ Kb, float* __restrict__ Mcol, float* __restrict__ Mrow){
  __shared__ u16 Kl[8*16*128];   // [q*16+h][w ^ (h<<2)]  32KB
  __shared__ u16 Vl[4*16*128];   // [c*16+h][w ^ (h<<2)]  16KB
  int b  = blockIdx.x >> 4;
  int ct = blockIdx.x & 15;
  int t  = threadIdx.x;
  float macc[16];
  #pragma unroll
  for (int i=0;i<16;i++) macc[i] = 0.f;
  const u32* kg = (const u32*)(Kb + (size_t)b*QD*HWn);
  const u32* vg = (const u32*)(Vb + ((size_t)b*Cn + ct*4)*HWn);

  for (int ht = 0; ht < Hn/16; ++ht){
    int h0 = ht*16;
    #pragma unroll
    for (int r=0;r<32;r++){
      int f = r*256 + t;
      int q = f >> 10, h = (f >> 6) & 15, w2 = f & 63;
      u32 kv = kg[(size_t)q*(HWn/2) + (size_t)(h0+h)*(Wn/2) + w2];
      int wi = (w2*2) ^ (h<<2);
      *(u32*)&Kl[(q*16+h)*128 + wi] = kv;
    }
    #pragma unroll
    for (int r=0;r<16;r++){
      int f = r*256 + t;
      int c = f >> 10, h = (f >> 6) & 15, w2 = f & 63;
      u32 vv = vg[(size_t)c*(HWn/2) + (size_t)(h0+h)*(Wn/2) + w2];
      int wi = (w2*2) ^ (h<<2);
      *(u32*)&Vl[(c*16+h)*128 + wi] = vv;
    }
    __syncthreads();
    // ---- Mrow: 512 outputs [c][q][h], 2/thread
    #pragma unroll
    for (int r=0;r<2;r++){
      int idx = r*256 + t;
      int c = idx >> 7, q = (idx >> 4) & 7, h = idx & 15;
      const u16* kr = &Kl[(q*16+h)*128];
      const u16* vr = &Vl[(c*16+h)*128];
      int hs = h << 2;
      float acc = 0.f;
      #pragma unroll 8
      for (int w4=0; w4<32; ++w4){
        int wi = (w4<<2) ^ hs;
        u32 k0 = *(const u32*)&kr[wi];
        u32 k1 = *(const u32*)&kr[wi+2];
        u32 v0 = *(const u32*)&vr[wi];
        u32 v1 = *(const u32*)&vr[wi+2];
        acc = fmaf(bfLO(v0), bfLO(k0), acc);
        acc = fmaf(bfHI(v0), bfHI(k0), acc);
        acc = fmaf(bfLO(v1), bfLO(k1), acc);
        acc = fmaf(bfHI(v1), bfHI(k1), acc);
      }
      Mrow[(((size_t)b*Cn + ct*4 + c)*QD + q)*Hn + h0 + h] = acc;
    }
    // ---- Mcol partials: [c][q][w-quad], 4 quads/thread, h-reduction
    #pragma unroll
    for (int r=0;r<4;r++){
      int idx = r*256 + t;
      int c = idx >> 8, q = (idx >> 5) & 7, w4 = idx & 31;
      float a0 = macc[r*4], a1 = macc[r*4+1], a2 = macc[r*4+2], a3 = macc[r*4+3];
      #pragma unroll 4
      for (int h=0; h<16; ++h){
        int wi = ((w4 ^ h) << 2);
        const u16* kr = &Kl[(q*16+h)*128];
        const u16* vr = &Vl[(c*16+h)*128];
        u32 k0 = *(const u32*)&kr[wi];
        u32 k1 = *(const u32*)&kr[wi+2];
        u32 v0 = *(const u32*)&vr[wi];
        u32 v1 = *(const u32*)&vr[wi+2];
        a0 = fmaf(bfLO(v0), bfLO(k0), a0);
        a1 = fmaf(bfHI(v0), bfHI(k0), a1);
        a2 = fmaf(bfLO(v1), bfLO(k1), a2);
        a3 = fmaf(bfHI(v1), bfHI(k1), a3);
      }
      macc[r*4] = a0; macc[r*4+1] = a1; macc[r*4+2] = a2; macc[r*4+3] = a3;
    }
    __syncthreads();
  }
  #pragma unroll
  for (int r=0;r<4;r++){
    int idx = r*256 + t;
    int c = idx >> 8, q = (idx >> 5) & 7, w4 = idx & 31;
    size_t o = (((size_t)b*Cn + ct*4 + c)*QD + q)*Wn + w4*4;
    float4 v; v.x = macc[r*4]; v.y = macc[r*4+1]; v.z = macc[r*4+2]; v.w = macc[r*4+3];
    *(float4*)&Mcol[o] = v;
  }
}

// ---------------------------------------------------------------------------
// Final: out = gamma*( sum_q Q[q,h,w]*(Mcol[c,q,w]+Mrow[c,q,h]) - 1e4*V[c,h,w] ) + x
template<bool BF>
__device__ __forceinline__ void final_impl(const void* __restrict__ xin,
    const u16* __restrict__ Qb, const u16* __restrict__ Vb,
    const float* __restrict__ Mcol, const float* __restrict__ Mrow,
    const float* __restrict__ gammaF, void* __restrict__ outp, float* mr){
  int b = blockIdx.x >> 4;
  int ht = blockIdx.x & 15;
  int w = threadIdx.x & 127;
  int s = threadIdx.x >> 7;
  int h0 = ht*8;
  float gma = gammaF[0];
  for (int idx = threadIdx.x; idx < Cn*8*QD; idx += 256){
    int c = idx >> 6; int rem = idx & 63; int q = rem >> 3; int hl = rem & 7;
    mr[(c*8 + hl)*QD + q] = Mrow[(((size_t)b*Cn + c)*QD + q)*Hn + h0 + hl];
  }
  __syncthreads();
  float Qr[4][QD];
  #pragma unroll
  for (int i=0;i<4;i++){
    int h = h0 + s*4 + i;
    #pragma unroll
    for (int q=0;q<QD;q++)
      Qr[i][q] = bf2f(Qb[(((size_t)b*QD + q)*Hn + h)*Wn + w]);
  }
  for (int c=0;c<Cn;c++){
    float Mc[QD];
    #pragma unroll
    for (int q=0;q<QD;q++)
      Mc[q] = Mcol[(((size_t)b*Cn + c)*QD + q)*Wn + w];
    size_t base = ((size_t)b*Cn + c)*HWn + (size_t)h0*Wn + w;
    #pragma unroll
    for (int i=0;i<4;i++){
      int hl = s*4 + i;
      size_t off = base + (size_t)hl*Wn;
      float v = bf2f(Vb[off]);
      float acc = NEGV * v;
      #pragma unroll
      for (int q=0;q<QD;q++)
        acc = fmaf(Qr[i][q], Mc[q] + mr[(c*8 + hl)*QD + q], acc);
      float xv = BF ? bf2f(((const u16*)xin)[off]) : ((const float*)xin)[off];
      float res = fmaf(gma, acc, xv);
      if (BF) ((u16*)outp)[off] = f2bf(res);
      else    ((float*)outp)[off] = res;
    }
  }
}

__global__ __launch_bounds__(256) void k_final(const void* __restrict__ xin,
    const int* __restrict__ flag, const u16* __restrict__ Qb,
    const u16* __restrict__ Vb, const float* __restrict__ Mcol,
    const float* __restrict__ Mrow, const float* __restrict__ gammaF,
    void* __restrict__ outp){
  __shared__ float mr[Cn*8*QD];
  if (flag[0]) final_impl<true >(xin, Qb, Vb, Mcol, Mrow, gammaF, outp, mr);
  else         final_impl<false>(xin, Qb, Vb, Mcol, Mrow, gammaF, outp, mr);
}

// ---------------------------------------------------------------------------
extern "C" void kernel_launch(void* const* d_in, const int* in_sizes, int n_in,
                              void* d_out, int out_size, void* d_ws, size_t ws_size,
                              hipStream_t stream){
  char* ws = (char*)d_ws;
  // workspace layout (bytes):
  u16*   Qb     = (u16*)  (ws);                        //  8,388,608 (bf16)
  u16*   Kb     = (u16*)  (ws + 8388608);              //  8,388,608 (bf16)
  float* Mcol   = (float*)(ws + 16777216);             //  8,388,608
  float* Mrow   = (float*)(ws + 25165824);             //  8,388,608
  float* Wall   = (float*)(ws + 33554432);             //     20,480
  float* biasv  = (float*)(ws + 33574912);             //        320
  float* gammaF = (float*)(ws + 33575232);             //          4
  int*   flag   = (int*)  (ws + 33575236);             //          4
  u16*   Vb     = (u16*)  (ws + 33575424);             // 67,108,864 (ends ~96MB)

  k_setup<<<1, 256, 0, stream>>>(d_in[1], d_in[2], d_in[3], d_in[4],
                                 d_in[5], d_in[6], d_in[7], flag,
                                 Wall, biasv, gammaF);
  k_proj<<<Bn*(HWn/512), 256, 0, stream>>>(d_in[0], flag, Wall, biasv, Qb, Kb, Vb);
  k_msum<<<Bn*16, 256, 0, stream>>>(Vb, Kb, Mcol, Mrow);
  k_final<<<Bn*16, 256, 0, stream>>>(d_in[0], flag, Qb, Vb, Mcol, Mrow, gammaF, d_out);
}